// Round 8
// baseline (704.305 us; speedup 1.0000x reference)
//
#include <hip/hip_runtime.h>
#include <math.h>

#define BB 256
#define NN 65536
#define NT 1024
#define CAP 2048
#define MARGIN 2e-3f

// Monotonic map: float order == uint order (ascending), and inverse
__device__ __forceinline__ unsigned int f2sort(float f) {
    unsigned int b = __float_as_uint(f);
    return (b & 0x80000000u) ? ~b : (b | 0x80000000u);
}
__device__ __forceinline__ float sort2f(unsigned int u) {
    unsigned int b = (u & 0x80000000u) ? (u & 0x7fffffffu) : ~u;
    return __uint_as_float(b);
}

// Bit-exact vs numpy f32 (f64 log rounded to f32) — band + fallback only
__device__ __forceinline__ unsigned int wexact(float u, float d) {
    float t1 = u + 1e-7f;
    float t2 = (float)log((double)t1);
    float t3 = (-t2) + 1e-7f;
    float G  = -(float)log((double)t3);
    float lgD = (float)log((double)d);
    return f2sort(G + lgD);
}

// Fast path: hw v_log_f32; |err| <= ~2e-5 abs near any cutoff; MARGIN 100x that.
__device__ __forceinline__ unsigned int wfast(float u, float d) {
    float t1 = u + 1e-7f;
    float t3 = -__logf(t1) + 1e-7f;
    float G  = -__logf(t3);
    return f2sort(G + __logf(d));
}

__device__ __forceinline__ bool finite_f(float f) {
    return (__float_as_uint(f) & 0x7f800000u) != 0x7f800000u;
}

// fallback scan macros (8192 / 1024 / 512 bins) — verified in R4
#define PASS1SEL(KKV) \
    { const int b0 = tid * 8; unsigned int cs = 0; \
      _Pragma("unroll") for (int i = 0; i < 8; i++) cs += hist[b0 + i]; \
      chunkSum[tid] = cs; } \
    __syncthreads(); \
    if (tid < 64) { \
        const int c0i = lane * 16; unsigned int s = 0; \
        _Pragma("unroll") for (int i = 0; i < 16; i++) s += chunkSum[c0i + i]; \
        unsigned int suf = s; \
        _Pragma("unroll") for (int off = 1; off < 64; off <<= 1) { \
            unsigned int tv = __shfl_down(suf, off); if (lane + off < 64) suf += tv; } \
        unsigned int above = suf - s; \
        if (suf >= (KKV) && above < (KKV)) { \
            unsigned int cum = above; \
            for (int ci = c0i + 15; ci >= c0i; ci--) { \
                unsigned int cch = chunkSum[ci]; \
                if (cum + cch >= (KKV)) { \
                    for (int b = ci * 8 + 7; ; b--) { \
                        unsigned int c2 = hist[b]; \
                        if (cum + c2 >= (KKV)) { s_sel = (unsigned int)b; s_kneed = (KKV) - cum; s_eq = c2; break; } \
                        cum += c2; } \
                    break; } \
                cum += cch; } } } \
    __syncthreads();

#define PASS2SEL(P, KN) \
    if (tid < 64) { \
        const int c0i = lane * 16; unsigned int s = 0; \
        _Pragma("unroll") for (int i = 0; i < 16; i++) s += hist[c0i + i]; \
        unsigned int suf = s; \
        _Pragma("unroll") for (int off = 1; off < 64; off <<= 1) { \
            unsigned int tv = __shfl_down(suf, off); if (lane + off < 64) suf += tv; } \
        unsigned int above = suf - s; \
        if (suf >= (KN) && above < (KN)) { \
            unsigned int cum = above; \
            for (int b = c0i + 15; ; b--) { \
                unsigned int c2 = hist[b]; \
                if (cum + c2 >= (KN)) { s_sel = ((P) << 10) | (unsigned int)b; s_kneed = (KN) - cum; s_eq = c2; break; } \
                cum += c2; } } } \
    __syncthreads();

#define PASS3SEL(P, KN) \
    if (tid < 64) { \
        const int c0i = lane * 8; unsigned int s = 0; \
        _Pragma("unroll") for (int i = 0; i < 8; i++) s += hist[c0i + i]; \
        unsigned int suf = s; \
        _Pragma("unroll") for (int off = 1; off < 64; off <<= 1) { \
            unsigned int tv = __shfl_down(suf, off); if (lane + off < 64) suf += tv; } \
        unsigned int above = suf - s; \
        if (suf >= (KN) && above < (KN)) { \
            unsigned int cum = above; \
            for (int b = c0i + 7; ; b--) { \
                unsigned int c2 = hist[b]; \
                if (cum + c2 >= (KN)) { s_sel = ((P) << 9) | (unsigned int)b; s_kneed = (KN) - cum; s_eq = c2; break; } \
                cum += c2; } } } \
    __syncthreads();

__global__ __launch_bounds__(NT)
void md_fused_kernel(const float* __restrict__ Tt,
                     const float* __restrict__ U,
                     const float* __restrict__ D,
                     float* __restrict__ out,     // [B,N] mask
                     float* __restrict__ wout) {  // [B] weights
    const int row = blockIdx.x;
    const int tid = threadIdx.x;
    const int lane = tid & 63;

    const float* Ur = U + (size_t)row * NN;
    const float* Dr = D + (size_t)row * NN;
    float* Or = out + (size_t)row * NN;

    // ---- LDS overlay: 159744 B total ----
    // [0,131072)        sval u16[65536]          | fallback: ehist[8192] + echunk
    // [131072,139264)   h11[2048] pass1 hist     | later: bitmap[2048]
    // [139264,143360)   csum[1024]
    // [143360,151552)   bandIdx[2048]            | fallback: tielist[1024]
    // [151552,159744)   bandU[2048]
    __shared__ __align__(16) unsigned char smem[159744];
    unsigned short* sval = (unsigned short*)smem;
    unsigned int* h11   = (unsigned int*)(smem + 131072);
    unsigned int* bitmap = (unsigned int*)(smem + 131072);
    unsigned int* csum  = (unsigned int*)(smem + 139264);
    int* bandIdx        = (int*)(smem + 143360);
    unsigned int* bandU = (unsigned int*)(smem + 151552);

    __shared__ unsigned int s_b1, s_kneed1, s_b2;
    __shared__ int s_A, s_bandCnt;
    __shared__ unsigned int s_sel, s_kneed, s_eq;
    __shared__ int s_tiecnt, s_tieidx;

    // ---- per-thread k; f32 step-for-step like ref ----
    const float t = Tt[row];
    const float pf = (float)M_PI;
    float aa = pf * t;
    float bbv = aa * 0.5f;
    float c0 = (float)cos((double)bbv);
    float r  = 1.0f - c0;
    const int k = (int)(65536.0f * r);
    if (tid == 0) {
        float tadj = t * 0.998f + 0.001f;
        float arg  = (pf * tadj) * 0.5f;
        wout[row] = (float)(0.5 * M_PI) * (float)sin((double)arg);
    }

    if (k <= 0 || k >= NN) {
        const float fill = (k >= NN) ? 1.0f : 0.0f;
        float4 f4 = make_float4(fill, fill, fill, fill);
        for (int j = 0; j < 16; j++)
            *(float4*)(Or + j * 4096 + tid * 4) = f4;
        return;
    }
    const unsigned int kk = (unsigned int)k;

    // ---- compute approx weights -> sval16 in LDS + 11-bit histogram ----
    for (int i = tid; i < 2048; i += NT) h11[i] = 0;
    if (tid == 0) { s_A = 0; s_bandCnt = 0; }
    __syncthreads();

    for (int j = 0; j < 16; j++) {
        int e = j * 4096 + tid * 4;
        float4 u4 = *(const float4*)(Ur + e);
        float4 d4 = *(const float4*)(Dr + e);
        unsigned int w0 = wfast(u4.x, d4.x);
        unsigned int w1 = wfast(u4.y, d4.y);
        unsigned int w2 = wfast(u4.z, d4.z);
        unsigned int w3 = wfast(u4.w, d4.w);
        // pack four u16 truncations into one b64 LDS write
        uint2 pk;
        pk.x = (w0 >> 16) | (w1 & 0xFFFF0000u);
        pk.y = (w2 >> 16) | (w3 & 0xFFFF0000u);
        *(uint2*)(sval + e) = pk;
        atomicAdd(&h11[w0 >> 21], 1u);
        atomicAdd(&h11[w1 >> 21], 1u);
        atomicAdd(&h11[w2 >> 21], 1u);
        atomicAdd(&h11[w3 >> 21], 1u);
    }
    __syncthreads();

    // ---- pass 1 select: 2-bin chunk sums over 2048 bins ----
    {
        unsigned int cs = h11[2 * tid] + h11[2 * tid + 1];
        csum[tid] = cs;
    }
    __syncthreads();
    if (tid < 64) {
        const int c0i = lane * 16;
        unsigned int s = 0;
#pragma unroll
        for (int i = 0; i < 16; i++) s += csum[c0i + i];
        unsigned int suf = s;
#pragma unroll
        for (int off = 1; off < 64; off <<= 1) {
            unsigned int tv = __shfl_down(suf, off);
            if (lane + off < 64) suf += tv;
        }
        unsigned int above = suf - s;
        if (suf >= kk && above < kk) {
            unsigned int cum = above;
            for (int ci = c0i + 15; ci >= c0i; ci--) {
                unsigned int cch = csum[ci];
                if (cum + cch >= kk) {
                    for (int b = 2 * ci + 1; ; b--) {
                        unsigned int c2 = h11[b];
                        if (cum + c2 >= kk) { s_b1 = (unsigned int)b; s_kneed1 = kk - cum; break; }
                        cum += c2;
                    }
                    break;
                }
                cum += cch;
            }
        }
    }
    __syncthreads();

    // ---- pass 2: low 5 bits (32 bins) among top-11 matches ----
    const unsigned int b1 = s_b1;
    const unsigned int kn1 = s_kneed1;
    __syncthreads();
    if (tid < 32) h11[tid] = 0;
    __syncthreads();
    for (int j = 0; j < 16; j++) {
        int e = j * 4096 + tid * 4;
        uint2 pk = *(const uint2*)(sval + e);
        unsigned int s0 = pk.x & 0xFFFFu, s1 = pk.x >> 16;
        unsigned int s2 = pk.y & 0xFFFFu, s3 = pk.y >> 16;
        if ((s0 >> 5) == b1) atomicAdd(&h11[s0 & 31u], 1u);
        if ((s1 >> 5) == b1) atomicAdd(&h11[s1 & 31u], 1u);
        if ((s2 >> 5) == b1) atomicAdd(&h11[s2 & 31u], 1u);
        if ((s3 >> 5) == b1) atomicAdd(&h11[s3 & 31u], 1u);
    }
    __syncthreads();
    if (tid < 64) {
        unsigned int c = (lane < 32) ? h11[lane] : 0u;
        unsigned int suf = c;
#pragma unroll
        for (int off = 1; off < 64; off <<= 1) {
            unsigned int tv = __shfl_down(suf, off);
            if (lane + off < 64) suf += tv;
        }
        if (suf >= kn1 && (suf - c) < kn1) s_b2 = (unsigned int)lane;
    }
    __syncthreads();

    // ---- band bounds: T16 bucket +/- MARGIN, widened to 16-bit granularity ----
    const unsigned int T16 = (b1 << 5) | s_b2;
    const float loF = sort2f(T16 << 16) - MARGIN;
    const float hiF = sort2f((T16 << 16) | 0xFFFFu) + MARGIN;
    const bool badBand = !(finite_f(loF) && finite_f(hiF));
    const unsigned int lo16 = f2sort(loF) >> 16;
    const unsigned int hi16 = f2sort(hiF) >> 16;

    // ---- count definite-ins, gather band indices, zero bitmap ----
    {
        int cnt = 0;
        for (int j = 0; j < 16; j++) {
            int e = j * 4096 + tid * 4;
            uint2 pk = *(const uint2*)(sval + e);
            unsigned int s0 = pk.x & 0xFFFFu, s1 = pk.x >> 16;
            unsigned int s2 = pk.y & 0xFFFFu, s3 = pk.y >> 16;
            cnt += (int)(s0 > hi16) + (int)(s1 > hi16) + (int)(s2 > hi16) + (int)(s3 > hi16);
            if (s0 >= lo16 && s0 <= hi16) { int sl = atomicAdd(&s_bandCnt, 1); if (sl < CAP) bandIdx[sl] = e + 0; }
            if (s1 >= lo16 && s1 <= hi16) { int sl = atomicAdd(&s_bandCnt, 1); if (sl < CAP) bandIdx[sl] = e + 1; }
            if (s2 >= lo16 && s2 <= hi16) { int sl = atomicAdd(&s_bandCnt, 1); if (sl < CAP) bandIdx[sl] = e + 2; }
            if (s3 >= lo16 && s3 <= hi16) { int sl = atomicAdd(&s_bandCnt, 1); if (sl < CAP) bandIdx[sl] = e + 3; }
        }
#pragma unroll
        for (int off = 32; off >= 1; off >>= 1) cnt += __shfl_down(cnt, off);
        if (lane == 0) atomicAdd(&s_A, cnt);
        bitmap[tid] = 0;          // aliases h11 (dead)
        bitmap[tid + 1024] = 0;
    }
    __syncthreads();

    const int bandCnt = s_bandCnt;
    const int kb = k - s_A;
    const bool fb = badBand || (bandCnt > CAP) || (kb < 0) || (kb > bandCnt);

    if (!fb) {
        // exact re-eval of band elements (scattered, ~hundreds)
        for (int j = tid; j < bandCnt; j += NT) {
            int idx = bandIdx[j];
            bandU[j] = wexact(Ur[idx], Dr[idx]);
        }
        __syncthreads();
        // stable rank (desc value, asc index); winners set bitmap bit
        for (int j = tid; j < bandCnt; j += NT) {
            unsigned int me = bandU[j];
            int mi = bandIdx[j];
            int rk = 0;
            for (int i = 0; i < bandCnt; i++) {
                unsigned int o = bandU[i];
                rk += (int)((o > me) || (o == me && bandIdx[i] < mi));
            }
            if (rk < kb) atomicOr(&bitmap[mi >> 5], 1u << (mi & 31));
        }
        __syncthreads();
        // branch-free write
        const int bsh = (tid & 7) * 4;
        for (int j = 0; j < 16; j++) {
            int e = j * 4096 + tid * 4;
            uint2 pk = *(const uint2*)(sval + e);
            unsigned int wb = bitmap[j * 128 + (tid >> 3)];
            unsigned int s0 = pk.x & 0xFFFFu, s1 = pk.x >> 16;
            unsigned int s2 = pk.y & 0xFFFFu, s3 = pk.y >> 16;
            float4 m;
            m.x = ((s0 > hi16) || ((wb >> (bsh + 0)) & 1u)) ? 1.0f : 0.0f;
            m.y = ((s1 > hi16) || ((wb >> (bsh + 1)) & 1u)) ? 1.0f : 0.0f;
            m.z = ((s2 > hi16) || ((wb >> (bsh + 2)) & 1u)) ? 1.0f : 0.0f;
            m.w = ((s3 > hi16) || ((wb >> (bsh + 3)) & 1u)) ? 1.0f : 0.0f;
            *(float4*)(Or + e) = m;
        }
        return;
    }

    // ============ exact fallback: recompute-per-pass R4 algorithm ============
    {
        unsigned int* hist = (unsigned int*)smem;              // 8192 bins
        unsigned int* chunkSum = (unsigned int*)(smem + 32768);
        int* s_tielist = (int*)(smem + 143360);                // 1024 ints

        __syncthreads();
        for (int i = tid; i < 8192; i += NT) hist[i] = 0;
        __syncthreads();
        for (int j = 0; j < 16; j++) {
            int e = j * 4096 + tid * 4;
            float4 u4 = *(const float4*)(Ur + e);
            float4 d4 = *(const float4*)(Dr + e);
            atomicAdd(&hist[wexact(u4.x, d4.x) >> 19], 1u);
            atomicAdd(&hist[wexact(u4.y, d4.y) >> 19], 1u);
            atomicAdd(&hist[wexact(u4.z, d4.z) >> 19], 1u);
            atomicAdd(&hist[wexact(u4.w, d4.w) >> 19], 1u);
        }
        __syncthreads();

        PASS1SEL(kk)
        const unsigned int q13 = s_sel;
        const unsigned int en1 = s_kneed;
        for (int i = tid; i < 1024; i += NT) hist[i] = 0;
        __syncthreads();
        for (int j = 0; j < 16; j++) {
            int e = j * 4096 + tid * 4;
            float4 u4 = *(const float4*)(Ur + e);
            float4 d4 = *(const float4*)(Dr + e);
            unsigned int w0 = wexact(u4.x, d4.x), w1 = wexact(u4.y, d4.y);
            unsigned int w2 = wexact(u4.z, d4.z), w3 = wexact(u4.w, d4.w);
            if ((w0 >> 19) == q13) atomicAdd(&hist[(w0 >> 9) & 1023u], 1u);
            if ((w1 >> 19) == q13) atomicAdd(&hist[(w1 >> 9) & 1023u], 1u);
            if ((w2 >> 19) == q13) atomicAdd(&hist[(w2 >> 9) & 1023u], 1u);
            if ((w3 >> 19) == q13) atomicAdd(&hist[(w3 >> 9) & 1023u], 1u);
        }
        __syncthreads();
        PASS2SEL(q13, en1)

        const unsigned int q23 = s_sel;
        const unsigned int en2 = s_kneed;
        if (tid < 512) hist[tid] = 0;
        __syncthreads();
        for (int j = 0; j < 16; j++) {
            int e = j * 4096 + tid * 4;
            float4 u4 = *(const float4*)(Ur + e);
            float4 d4 = *(const float4*)(Dr + e);
            unsigned int w0 = wexact(u4.x, d4.x), w1 = wexact(u4.y, d4.y);
            unsigned int w2 = wexact(u4.z, d4.z), w3 = wexact(u4.w, d4.w);
            if ((w0 >> 9) == q23) atomicAdd(&hist[w0 & 511u], 1u);
            if ((w1 >> 9) == q23) atomicAdd(&hist[w1 & 511u], 1u);
            if ((w2 >> 9) == q23) atomicAdd(&hist[w2 & 511u], 1u);
            if ((w3 >> 9) == q23) atomicAdd(&hist[w3 & 511u], 1u);
        }
        __syncthreads();
        PASS3SEL(q23, en2)

        const unsigned int theta = s_sel;
        const unsigned int kneedF = s_kneed, eqF = s_eq;
        const bool needOrder = (kneedF < eqF);
        int istar = NN;
        if (needOrder) {
            if (tid == 0) s_tiecnt = 0;
            __syncthreads();
            for (int j = 0; j < 16; j++) {
                int e = j * 4096 + tid * 4;
                float4 u4 = *(const float4*)(Ur + e);
                float4 d4 = *(const float4*)(Dr + e);
                unsigned int w[4] = {wexact(u4.x, d4.x), wexact(u4.y, d4.y),
                                     wexact(u4.z, d4.z), wexact(u4.w, d4.w)};
                for (int c = 0; c < 4; c++)
                    if (w[c] == theta) {
                        int pos = atomicAdd(&s_tiecnt, 1);
                        if (pos < 1024) s_tielist[pos] = e + c;
                    }
            }
            __syncthreads();
            if (tid == 0) {
                int E = s_tiecnt; if (E > 1024) E = 1024;
                for (int aI = 1; aI < E; aI++) {
                    int val = s_tielist[aI]; int bI = aI - 1;
                    while (bI >= 0 && s_tielist[bI] > val) { s_tielist[bI + 1] = s_tielist[bI]; bI--; }
                    s_tielist[bI + 1] = val;
                }
                int kk2 = (int)kneedF; if (kk2 > E) kk2 = E; if (kk2 < 1) kk2 = 1;
                s_tieidx = s_tielist[kk2 - 1];
            }
            __syncthreads();
            istar = s_tieidx;
        }

        for (int j = 0; j < 16; j++) {
            int e = j * 4096 + tid * 4;
            float4 u4 = *(const float4*)(Ur + e);
            float4 d4 = *(const float4*)(Dr + e);
            unsigned int w[4] = {wexact(u4.x, d4.x), wexact(u4.y, d4.y),
                                 wexact(u4.z, d4.z), wexact(u4.w, d4.w)};
            float4 m;
            float* mp = &m.x;
            for (int c = 0; c < 4; c++) {
                bool in = (w[c] > theta) || (w[c] == theta && (!needOrder || (e + c) <= istar));
                mp[c] = in ? 1.0f : 0.0f;
            }
            *(float4*)(Or + e) = m;
        }
    }
}

extern "C" void kernel_launch(void* const* d_in, const int* in_sizes, int n_in,
                              void* d_out, int out_size, void* d_ws, size_t ws_size,
                              hipStream_t stream) {
    // inputs: batch[B*N] i32 (unused), t[B] f32, U[B*N] f32, D[B*N] f32
    const float* T = (const float*)d_in[1];
    const float* U = (const float*)d_in[2];
    const float* D = (const float*)d_in[3];
    float* out = (float*)d_out;
    float* wout = out + (size_t)BB * NN;

    md_fused_kernel<<<BB, NT, 0, stream>>>(T, U, D, out, wout);
}